// Round 4
// baseline (287.345 us; speedup 1.0000x reference)
//
#include <hip/hip_runtime.h>
#include <hip/hip_bf16.h>
#include <math.h>

#define BB 4
#define NN 3000
#define FF 128
#define NKC 94          // number of 32-wide K chunks (94*32 = 3008 >= 3000)
#define NIT 188         // number of 16-row tiles (188*16 = 3008)

typedef __bf16 bf16x8 __attribute__((ext_vector_type(8)));
typedef float  f32x4  __attribute__((ext_vector_type(4)));

// ---------------- K1: fused degree + A-pack ----------------
// Per block: one 16-row tile of adj. Streams the rows once (coalesced float4),
// accumulating row sums (-> dis) and re-emitting the tile as bf16 in MFMA
// A-fragment order: apk[b][it][kc][lane][8], lane = m + 16*quad,
// element = adj[i0+m][kc*32 + quad*8 + j].
__global__ __launch_bounds__(256) void k_degpack(const float* __restrict__ adj,
                                                 __bf16* __restrict__ apk,
                                                 float* __restrict__ dis) {
    __shared__ float tile[16][260];
    const int b  = blockIdx.y;
    const int it = blockIdx.x;
    const int i0 = it * 16;
    const int t  = threadIdx.x, w = t >> 6, l = t & 63;
    const int m  = l & 15, quad = l >> 4;
    float dreg[4] = {0.f, 0.f, 0.f, 0.f};
    __bf16* dst = apk + ((size_t)(b * NIT + it) * NKC) * 512 + l * 8;
    for (int c = 0; c < 12; ++c) {
        int k0 = c * 256;
        #pragma unroll
        for (int i = 0; i < 4; ++i) {
            int row = i * 4 + w;
            int col = k0 + l * 4;
            float4 v = {0.f, 0.f, 0.f, 0.f};
            if (i0 + row < NN && col < NN)
                v = *(const float4*)(adj + ((size_t)b * NN + i0 + row) * NN + col);
            dreg[i] += (v.x + v.y) + (v.z + v.w);
            *(float4*)&tile[row][l * 4] = v;
        }
        __syncthreads();
        int nk = (c == 11) ? 6 : 8;   // last chunk: kc 88..93 (k 2816..3007)
        #pragma unroll
        for (int h = 0; h < 2; ++h) {
            int kcl = w + h * 4;
            if (kcl < nk) {
                bf16x8 a;
                #pragma unroll
                for (int j = 0; j < 8; ++j)
                    a[j] = (__bf16)tile[m][kcl * 32 + quad * 8 + j];
                *(bf16x8*)(dst + (size_t)(c * 8 + kcl) * 512) = a;
            }
        }
        __syncthreads();
    }
    // reduce row sums: wave w owns rows {w, 4+w, 8+w, 12+w}
    #pragma unroll
    for (int i = 0; i < 4; ++i) {
        float s = dreg[i];
        for (int off = 32; off > 0; off >>= 1) s += __shfl_down(s, off, 64);
        int irow = i0 + i * 4 + w;
        if (l == 0 && irow < NN) dis[b * NN + irow] = 1.0f / sqrtf(s + 1.0f);
    }
}

// ---------------- K2: pack xs = dis_k * x[k][f] into MFMA B-fragment order ------
// xpk[b][nt][kc][lane][8], lane = (f%16) + 16*quad, k = kc*32 + quad*8 + j.
__global__ __launch_bounds__(256) void k_xpk(const float* __restrict__ x,
                                             const float* __restrict__ dis,
                                             __bf16* __restrict__ xpk) {
    int b  = blockIdx.y, kc = blockIdx.x;
    int t  = threadIdx.x, w = t >> 6, l = t & 63;
    int m  = l & 15, q = l >> 4;
    #pragma unroll
    for (int h = 0; h < 2; ++h) {
        int nt = w + h * 4;
        int f  = nt * 16 + m;
        bf16x8 v;
        #pragma unroll
        for (int j = 0; j < 8; ++j) {
            int k = kc * 32 + q * 8 + j;
            float val = 0.f;
            if (k < NN) val = dis[b * NN + k] * x[((size_t)b * NN + k) * FF + f];
            v[j] = (__bf16)val;
        }
        *(bf16x8*)(xpk + ((size_t)(b * 8 + nt) * NKC + kc) * 512 + l * 8) = v;
    }
}

// ---------------- K2b: pack theta into MFMA B-fragment order --------------------
__global__ __launch_bounds__(256) void k_thpk(const float* __restrict__ theta,
                                              __bf16* __restrict__ thpk) {
    int kc = blockIdx.x;
    int t  = threadIdx.x, w = t >> 6, l = t & 63;
    int m  = l & 15, q = l >> 4;
    #pragma unroll
    for (int h = 0; h < 2; ++h) {
        int nt = w + h * 4;
        bf16x8 v;
        #pragma unroll
        for (int j = 0; j < 8; ++j) {
            int k = kc * 32 + q * 8 + j;
            v[j] = (__bf16)theta[k * FF + nt * 16 + m];
        }
        *(bf16x8*)(thpk + ((size_t)(nt * 4 + kc)) * 512 + l * 8) = v;
    }
}

// ---------------- K3 (fused): out = beta*(support@theta) + (1-beta)*support ------
// support = (1-alpha)*hi + alpha*h0,  hi_i = dis_i*(adj_i . xs) + dis_i^2 * x_i
// Main loop: pure fragment streaming (A from apk, B from xpk), no LDS, no barriers.
__global__ __launch_bounds__(256) void k_agg(const __bf16* __restrict__ apk,
                                             const __bf16* __restrict__ xpk,
                                             const __bf16* __restrict__ thpk,
                                             const float* __restrict__ x,
                                             const float* __restrict__ h0,
                                             const float* __restrict__ dis,
                                             float* __restrict__ out,
                                             const float* __restrict__ alpha_p,
                                             const float* __restrict__ lamda_p,
                                             const int* __restrict__ l_p) {
    __shared__ __bf16 stile[16][136];
    const int b  = blockIdx.y;
    const int it = blockIdx.x;
    const int i0 = it * 16;
    const int t  = threadIdx.x, w = t >> 6, l = t & 63;
    const int m  = l & 15, quad = l >> 4;
    const int n0 = w * 32;
    const __bf16* Ap = apk + ((size_t)(b * NIT + it) * NKC) * 512 + l * 8;
    const __bf16* B0 = xpk + ((size_t)(b * 8 + 2 * w) * NKC) * 512 + l * 8;
    const __bf16* B1 = B0 + (size_t)NKC * 512;
    f32x4 acc0 = {0.f, 0.f, 0.f, 0.f};
    f32x4 acc1 = {0.f, 0.f, 0.f, 0.f};
    #pragma unroll 2
    for (int kc = 0; kc < NKC; ++kc) {
        bf16x8 a  = *(const bf16x8*)(Ap + (size_t)kc * 512);
        bf16x8 b0 = *(const bf16x8*)(B0 + (size_t)kc * 512);
        bf16x8 b1 = *(const bf16x8*)(B1 + (size_t)kc * 512);
        acc0 = __builtin_amdgcn_mfma_f32_16x16x32_bf16(a, b0, acc0, 0, 0, 0);
        acc1 = __builtin_amdgcn_mfma_f32_16x16x32_bf16(a, b1, acc1, 0, 0, 0);
    }
    // ---- epilogue: support values; stage tile in A-layout (bf16) ----
    const float alpha = *alpha_p;
    const float beta  = logf(*lamda_p / (float)(*l_p) + 1.0f);
    float s0v[4], s1v[4];
    #pragma unroll
    for (int r = 0; r < 4; ++r) {
        int row  = quad * 4 + r;
        int irow = i0 + row;
        float s0 = 0.f, s1 = 0.f;
        if (irow < NN) {
            float  di   = dis[b * NN + irow];
            size_t base = ((size_t)b * NN + irow) * FF;
            int c0 = n0 + m, c1 = n0 + 16 + m;
            s0 = (1.f - alpha) * (di * acc0[r] + di * di * x[base + c0]) + alpha * h0[base + c0];
            s1 = (1.f - alpha) * (di * acc1[r] + di * di * x[base + c1]) + alpha * h0[base + c1];
        }
        s0v[r] = s0; s1v[r] = s1;
        stile[row][n0 + m]      = (__bf16)s0;
        stile[row][n0 + 16 + m] = (__bf16)s1;
    }
    __syncthreads();
    // ---- theta matmul on the 16x128 support tile ----
    f32x4 o0 = {0.f, 0.f, 0.f, 0.f};
    f32x4 o1 = {0.f, 0.f, 0.f, 0.f};
    const __bf16* T0 = thpk + (size_t)(2 * w * 4) * 512 + l * 8;
    const __bf16* T1 = T0 + 4 * 512;
    #pragma unroll
    for (int kc = 0; kc < 4; ++kc) {
        bf16x8 a   = *(const bf16x8*)&stile[m][kc * 32 + quad * 8];
        bf16x8 tb0 = *(const bf16x8*)(T0 + (size_t)kc * 512);
        bf16x8 tb1 = *(const bf16x8*)(T1 + (size_t)kc * 512);
        o0 = __builtin_amdgcn_mfma_f32_16x16x32_bf16(a, tb0, o0, 0, 0, 0);
        o1 = __builtin_amdgcn_mfma_f32_16x16x32_bf16(a, tb1, o1, 0, 0, 0);
    }
    const float omb = 1.f - beta;
    #pragma unroll
    for (int r = 0; r < 4; ++r) {
        int irow = i0 + quad * 4 + r;
        if (irow < NN) {
            size_t base = ((size_t)b * NN + irow) * FF;
            out[base + n0 + m]      = beta * o0[r] + omb * s0v[r];
            out[base + n0 + 16 + m] = beta * o1[r] + omb * s1v[r];
        }
    }
}

extern "C" void kernel_launch(void* const* d_in, const int* in_sizes, int n_in,
                              void* d_out, int out_size, void* d_ws, size_t ws_size,
                              hipStream_t stream) {
    const float* x      = (const float*)d_in[0];
    const float* adj    = (const float*)d_in[1];
    const float* h0     = (const float*)d_in[2];
    const float* theta  = (const float*)d_in[3];
    const float* lamda  = (const float*)d_in[4];
    const float* alpha  = (const float*)d_in[5];
    const int*   l      = (const int*)d_in[6];
    float* out = (float*)d_out;

    char*   ws   = (char*)d_ws;
    float*  dis  = (float*)ws;                         // 48,000 B
    __bf16* xpk  = (__bf16*)(ws + 65536);              // 3,080,192 B
    __bf16* thpk = (__bf16*)(ws + 3200000);            // 32,768 B
    __bf16* apk  = (__bf16*)(ws + 4 * 1024 * 1024);    // 4*188*94*1024 = 72,384,512 B

    k_degpack<<<dim3(NIT, BB), 256, 0, stream>>>(adj, apk, dis);
    k_thpk<<<dim3(4), 256, 0, stream>>>(theta, thpk);
    k_xpk<<<dim3(NKC, BB), 256, 0, stream>>>(x, dis, xpk);
    k_agg<<<dim3(NIT, BB), 256, 0, stream>>>(apk, xpk, thpk, x, h0, dis, out,
                                             alpha, lamda, l);
}